// Round 3
// baseline (106.407 us; speedup 1.0000x reference)
//
#include <hip/hip_runtime.h>
#include <hip/hip_fp16.h>
#include <math.h>

#define EMB_DIM 500
#define TWO_D 1000
#define D4 125                 // float4 groups per half-row (500/4)
#define ROW_F4 250             // float4 per entity row (1000/4)
#define NUM_ENTITIES 14541
#define B_SIZE 16
#define GAMMA_F 12.0f
// PI / ((GAMMA + 2) / EMB_DIM) = pi / 0.028
#define PHASE_SCALE 112.19973762820692f
#define ROT_HALFS (B_SIZE * D4 * 8)   // 16000 halfs = 32000 B
#define ENT_PER_WAVE 2
#define ENT_PER_BLOCK 8

// ---------------------------------------------------------------------------
// Kernel 1: precompute rotated head embeddings as fp16, interleaved layout
// rot[b][d4][0..3] = re(4*d4 .. 4*d4+3), rot[b][d4][4..7] = im(...)
// ---------------------------------------------------------------------------
__global__ __launch_bounds__(256) void rot_precompute(
    const int* __restrict__ all_h, const int* __restrict__ all_r,
    const float* __restrict__ eemb, const float* __restrict__ remb,
    __half* __restrict__ rot)
{
    int i = blockIdx.x * 256 + threadIdx.x;
    if (i >= B_SIZE * EMB_DIM) return;
    int b = i / EMB_DIM;
    int d = i - b * EMB_DIM;
    int h = all_h[b];
    int r = all_r[b];
    float re_h = eemb[h * TWO_D + d];
    float im_h = eemb[h * TWO_D + EMB_DIM + d];
    float ph = remb[r * EMB_DIM + d] * PHASE_SCALE;
    float s, c;
    sincosf(ph, &s, &c);
    int base = ((b * D4 + (d >> 2)) << 3) + (d & 3);
    rot[base]     = __float2half(re_h * c - im_h * s);  // re_rot
    rot[base + 4] = __float2half(re_h * s + im_h * c);  // im_rot
}

// ---------------------------------------------------------------------------
// Kernel 2: one block = 8 entities (2 per wave) -> 32 accumulators per lane,
// no spill. Rot table (32 KB fp16) in LDS; entity rows streamed via float4.
// ---------------------------------------------------------------------------
__global__ __launch_bounds__(256, 4) void rotate_score(
    const float* __restrict__ eemb,
    const __half* __restrict__ rot,      // nullptr -> compute in-kernel
    const int* __restrict__ all_h, const int* __restrict__ all_r,
    const float* __restrict__ remb,
    float* __restrict__ out)
{
    __shared__ __half lrot[ROT_HALFS];   // 32000 bytes

    const int tid = threadIdx.x;

    if (rot != nullptr) {
        const float4* src = (const float4*)rot;
        float4* dst = (float4*)lrot;
        for (int i = tid; i < ROT_HALFS / 8; i += 256) dst[i] = src[i];
    } else {
        for (int i = tid; i < B_SIZE * EMB_DIM; i += 256) {
            int b = i / EMB_DIM;
            int d = i - b * EMB_DIM;
            int h = all_h[b];
            int r = all_r[b];
            float re_h = eemb[h * TWO_D + d];
            float im_h = eemb[h * TWO_D + EMB_DIM + d];
            float ph = remb[r * EMB_DIM + d] * PHASE_SCALE;
            float s, c;
            sincosf(ph, &s, &c);
            int base = ((b * D4 + (d >> 2)) << 3) + (d & 3);
            lrot[base]     = __float2half(re_h * c - im_h * s);
            lrot[base + 4] = __float2half(re_h * s + im_h * c);
        }
    }
    __syncthreads();

    const int lane = tid & 63;
    const int wave = tid >> 6;
    const int e0 = blockIdx.x * ENT_PER_BLOCK + wave * ENT_PER_WAVE;

    int e[ENT_PER_WAVE];
#pragma unroll
    for (int k = 0; k < ENT_PER_WAVE; ++k) {
        int ek = e0 + k;
        e[k] = (ek < NUM_ENTITIES) ? ek : (NUM_ENTITIES - 1);
    }

    float v[32];                         // acc[k][b]: idx = k*16+b
#pragma unroll
    for (int i = 0; i < 32; ++i) v[i] = 0.0f;

    const float4* lrot4 = (const float4*)lrot;
    const float4* ee4 = (const float4*)eemb;

#pragma unroll
    for (int it = 0; it < 2; ++it) {
        const int d4 = it * 64 + lane;
        if (d4 < D4) {
            float4 tre[ENT_PER_WAVE], tim[ENT_PER_WAVE];
#pragma unroll
            for (int k = 0; k < ENT_PER_WAVE; ++k) {
                int rb = e[k] * ROW_F4;
                tre[k] = ee4[rb + d4];
                tim[k] = ee4[rb + D4 + d4];
            }
#pragma unroll
            for (int b = 0; b < 16; ++b) {
                float4 rv = lrot4[b * D4 + d4];
                __half2 p0 = __builtin_bit_cast(__half2, rv.x);
                __half2 p1 = __builtin_bit_cast(__half2, rv.y);
                __half2 p2 = __builtin_bit_cast(__half2, rv.z);
                __half2 p3 = __builtin_bit_cast(__half2, rv.w);
                float rre0 = __low2float(p0), rre1 = __high2float(p0);
                float rre2 = __low2float(p1), rre3 = __high2float(p1);
                float rim0 = __low2float(p2), rim1 = __high2float(p2);
                float rim2 = __low2float(p3), rim3 = __high2float(p3);
#pragma unroll
                for (int k = 0; k < ENT_PER_WAVE; ++k) {
                    float dre, dim;
                    dre = rre0 - tre[k].x; dim = rim0 - tim[k].x;
                    v[k * 16 + b] += __builtin_amdgcn_sqrtf(dre * dre + dim * dim);
                    dre = rre1 - tre[k].y; dim = rim1 - tim[k].y;
                    v[k * 16 + b] += __builtin_amdgcn_sqrtf(dre * dre + dim * dim);
                    dre = rre2 - tre[k].z; dim = rim2 - tim[k].z;
                    v[k * 16 + b] += __builtin_amdgcn_sqrtf(dre * dre + dim * dim);
                    dre = rre3 - tre[k].w; dim = rim3 - tim[k].w;
                    v[k * 16 + b] += __builtin_amdgcn_sqrtf(dre * dre + dim * dim);
                }
            }
        }
    }

    // Stage 1: fold the two 32-lane halves (lanes l and l^32 become equal).
#pragma unroll
    for (int i = 0; i < 32; ++i) v[i] += __shfl_xor(v[i], 32, 64);

    // Stages 2-6: halving butterfly over the low 5 lane bits; afterwards
    // lane L (0..31) holds the full 64-lane sum of acc[L].
#pragma unroll
    for (int m = 16; m >= 1; m >>= 1) {
        const bool hi = (lane & m) != 0;
#pragma unroll
        for (int i = 0; i < m; ++i) {
            float give = hi ? v[i] : v[m + i];
            float keep = hi ? v[m + i] : v[i];
            v[i] = keep + __shfl_xor(give, m, 64);
        }
    }

    if (lane < 32) {
        const int kk = lane >> 4;        // 0..1
        const int bb = lane & 15;        // 0..15
        const int ee = e0 + kk;
        if (ee < NUM_ENTITIES) out[bb * NUM_ENTITIES + ee] = GAMMA_F - v[0];
    }
}

extern "C" void kernel_launch(void* const* d_in, const int* in_sizes, int n_in,
                              void* d_out, int out_size, void* d_ws, size_t ws_size,
                              hipStream_t stream) {
    const int*   all_h = (const int*)d_in[0];
    const int*   all_r = (const int*)d_in[1];
    const float* eemb  = (const float*)d_in[2];
    const float* remb  = (const float*)d_in[3];
    float* out = (float*)d_out;

    __half* rot = nullptr;
    const size_t rot_bytes = (size_t)ROT_HALFS * sizeof(__half);
    if (ws_size >= rot_bytes) {
        rot = (__half*)d_ws;
        rot_precompute<<<(B_SIZE * EMB_DIM + 255) / 256, 256, 0, stream>>>(
            all_h, all_r, eemb, remb, rot);
    }

    int nblocks = (NUM_ENTITIES + ENT_PER_BLOCK - 1) / ENT_PER_BLOCK;  // 1818
    rotate_score<<<nblocks, 256, 0, stream>>>(eemb, rot, all_h, all_r, remb, out);
}

// Round 5
// 97.418 us; speedup vs baseline: 1.0923x; 1.0923x over previous
//
#include <hip/hip_runtime.h>
#include <hip/hip_fp16.h>
#include <math.h>

#define EMB_DIM 500
#define TWO_D 1000
#define D4 125                 // float4 groups per half-row (500/4)
#define ROW_F4 250             // float4 per entity row (1000/4)
#define NUM_ENTITIES 14541
#define B_SIZE 16
#define GAMMA_F 12.0f
// PI / ((GAMMA + 2) / EMB_DIM) = pi / 0.028
#define PHASE_SCALE 112.19973762820692f
#define ROT_HALFS (B_SIZE * D4 * 8)   // 16000 halfs = 32000 B
#define ENT_PER_WAVE 2
#define ENT_PER_BLOCK 8

// ---------------------------------------------------------------------------
// Kernel 1: precompute rotated head embeddings as fp16, interleaved layout
// rot[b][d4][0..3] = re(4*d4 .. 4*d4+3), rot[b][d4][4..7] = im(...)
// ---------------------------------------------------------------------------
__global__ __launch_bounds__(256) void rot_precompute(
    const int* __restrict__ all_h, const int* __restrict__ all_r,
    const float* __restrict__ eemb, const float* __restrict__ remb,
    __half* __restrict__ rot)
{
    int i = blockIdx.x * 256 + threadIdx.x;
    if (i >= B_SIZE * EMB_DIM) return;
    int b = i / EMB_DIM;
    int d = i - b * EMB_DIM;
    int h = all_h[b];
    int r = all_r[b];
    float re_h = eemb[h * TWO_D + d];
    float im_h = eemb[h * TWO_D + EMB_DIM + d];
    float ph = remb[r * EMB_DIM + d] * PHASE_SCALE;
    float s, c;
    sincosf(ph, &s, &c);
    int base = ((b * D4 + (d >> 2)) << 3) + (d & 3);
    rot[base]     = __float2half(re_h * c - im_h * s);  // re_rot
    rot[base + 4] = __float2half(re_h * s + im_h * c);  // im_rot
}

// ---------------------------------------------------------------------------
// Kernel 2: one block = 8 entities (2 per wave) -> 32 accumulators per lane.
// NOTE: no min-waves launch_bounds arg — with (256,4) the allocator targeted
// a 64-VGPR budget and spilled the accumulators to scratch (R3: WRITE_SIZE
// 109 MB, 106us). Plain (256) lets it take ~104-128 VGPRs (R1 evidence).
// ---------------------------------------------------------------------------
__global__ __launch_bounds__(256) void rotate_score(
    const float* __restrict__ eemb,
    const __half* __restrict__ rot,      // nullptr -> compute in-kernel
    const int* __restrict__ all_h, const int* __restrict__ all_r,
    const float* __restrict__ remb,
    float* __restrict__ out)
{
    __shared__ __half lrot[ROT_HALFS];   // 32000 bytes

    const int tid = threadIdx.x;

    if (rot != nullptr) {
        const float4* src = (const float4*)rot;
        float4* dst = (float4*)lrot;
        for (int i = tid; i < ROT_HALFS / 8; i += 256) dst[i] = src[i];
    } else {
        for (int i = tid; i < B_SIZE * EMB_DIM; i += 256) {
            int b = i / EMB_DIM;
            int d = i - b * EMB_DIM;
            int h = all_h[b];
            int r = all_r[b];
            float re_h = eemb[h * TWO_D + d];
            float im_h = eemb[h * TWO_D + EMB_DIM + d];
            float ph = remb[r * EMB_DIM + d] * PHASE_SCALE;
            float s, c;
            sincosf(ph, &s, &c);
            int base = ((b * D4 + (d >> 2)) << 3) + (d & 3);
            lrot[base]     = __float2half(re_h * c - im_h * s);
            lrot[base + 4] = __float2half(re_h * s + im_h * c);
        }
    }
    __syncthreads();

    const int lane = tid & 63;
    const int wave = tid >> 6;
    const int e0 = blockIdx.x * ENT_PER_BLOCK + wave * ENT_PER_WAVE;

    int e[ENT_PER_WAVE];
#pragma unroll
    for (int k = 0; k < ENT_PER_WAVE; ++k) {
        int ek = e0 + k;
        e[k] = (ek < NUM_ENTITIES) ? ek : (NUM_ENTITIES - 1);
    }

    float v[32];                         // acc[k][b]: idx = k*16+b
#pragma unroll
    for (int i = 0; i < 32; ++i) v[i] = 0.0f;

    const float4* lrot4 = (const float4*)lrot;
    const float4* ee4 = (const float4*)eemb;

#pragma unroll
    for (int it = 0; it < 2; ++it) {
        const int d4 = it * 64 + lane;
        if (d4 < D4) {
            float4 tre[ENT_PER_WAVE], tim[ENT_PER_WAVE];
#pragma unroll
            for (int k = 0; k < ENT_PER_WAVE; ++k) {
                int rb = e[k] * ROW_F4;
                tre[k] = ee4[rb + d4];
                tim[k] = ee4[rb + D4 + d4];
            }
#pragma unroll
            for (int b = 0; b < 16; ++b) {
                float4 rv = lrot4[b * D4 + d4];
                __half2 p0 = __builtin_bit_cast(__half2, rv.x);
                __half2 p1 = __builtin_bit_cast(__half2, rv.y);
                __half2 p2 = __builtin_bit_cast(__half2, rv.z);
                __half2 p3 = __builtin_bit_cast(__half2, rv.w);
                float rre0 = __low2float(p0), rre1 = __high2float(p0);
                float rre2 = __low2float(p1), rre3 = __high2float(p1);
                float rim0 = __low2float(p2), rim1 = __high2float(p2);
                float rim2 = __low2float(p3), rim3 = __high2float(p3);
#pragma unroll
                for (int k = 0; k < ENT_PER_WAVE; ++k) {
                    float dre, dim;
                    dre = rre0 - tre[k].x; dim = rim0 - tim[k].x;
                    v[k * 16 + b] += __builtin_amdgcn_sqrtf(dre * dre + dim * dim);
                    dre = rre1 - tre[k].y; dim = rim1 - tim[k].y;
                    v[k * 16 + b] += __builtin_amdgcn_sqrtf(dre * dre + dim * dim);
                    dre = rre2 - tre[k].z; dim = rim2 - tim[k].z;
                    v[k * 16 + b] += __builtin_amdgcn_sqrtf(dre * dre + dim * dim);
                    dre = rre3 - tre[k].w; dim = rim3 - tim[k].w;
                    v[k * 16 + b] += __builtin_amdgcn_sqrtf(dre * dre + dim * dim);
                }
            }
        }
    }

    // Stage 1: fold the two 32-lane halves (lanes l and l^32 become equal).
#pragma unroll
    for (int i = 0; i < 32; ++i) v[i] += __shfl_xor(v[i], 32, 64);

    // Stages 2-6: halving butterfly over the low 5 lane bits; afterwards
    // lane L (0..31) holds the full 64-lane sum of acc[L].
#pragma unroll
    for (int m = 16; m >= 1; m >>= 1) {
        const bool hi = (lane & m) != 0;
#pragma unroll
        for (int i = 0; i < m; ++i) {
            float give = hi ? v[i] : v[m + i];
            float keep = hi ? v[m + i] : v[i];
            v[i] = keep + __shfl_xor(give, m, 64);
        }
    }

    if (lane < 32) {
        const int kk = lane >> 4;        // 0..1
        const int bb = lane & 15;        // 0..15
        const int ee = e0 + kk;
        if (ee < NUM_ENTITIES) out[bb * NUM_ENTITIES + ee] = GAMMA_F - v[0];
    }
}

extern "C" void kernel_launch(void* const* d_in, const int* in_sizes, int n_in,
                              void* d_out, int out_size, void* d_ws, size_t ws_size,
                              hipStream_t stream) {
    const int*   all_h = (const int*)d_in[0];
    const int*   all_r = (const int*)d_in[1];
    const float* eemb  = (const float*)d_in[2];
    const float* remb  = (const float*)d_in[3];
    float* out = (float*)d_out;

    __half* rot = nullptr;
    const size_t rot_bytes = (size_t)ROT_HALFS * sizeof(__half);
    if (ws_size >= rot_bytes) {
        rot = (__half*)d_ws;
        rot_precompute<<<(B_SIZE * EMB_DIM + 255) / 256, 256, 0, stream>>>(
            all_h, all_r, eemb, remb, rot);
    }

    int nblocks = (NUM_ENTITIES + ENT_PER_BLOCK - 1) / ENT_PER_BLOCK;  // 1818
    rotate_score<<<nblocks, 256, 0, stream>>>(eemb, rot, all_h, all_r, remb, out);
}

// Round 9
// 39.033 us; speedup vs baseline: 2.7261x; 2.4958x over previous
//
#include <hip/hip_runtime.h>
#include <hip/hip_fp16.h>
#include <math.h>

#define EMB_DIM 500
#define TWO_D 1000
#define D4 125                 // float4 groups per half-row (500/4)
#define ROW_F4 250             // float4 per entity row (1000/4)
#define NUM_ENTITIES 14541
#define B_SIZE 16
#define GAMMA_F 12.0f
// PI / ((GAMMA + 2) / EMB_DIM) = pi / 0.028
#define PHASE_SCALE 112.19973762820692f
#define ROT_HALFS (B_SIZE * D4 * 8)   // 16000 halfs = 32000 B
#define ENT_PER_WAVE 4
#define ENT_PER_BLOCK 16

// ---------------------------------------------------------------------------
// Kernel 1: precompute rotated head embeddings as fp16, interleaved layout
// rot[b][d4][0..3] = re(4*d4 .. 4*d4+3), rot[b][d4][4..7] = im(...)
// ---------------------------------------------------------------------------
__global__ __launch_bounds__(256) void rot_precompute(
    const int* __restrict__ all_h, const int* __restrict__ all_r,
    const float* __restrict__ eemb, const float* __restrict__ remb,
    __half* __restrict__ rot)
{
    int i = blockIdx.x * 256 + threadIdx.x;
    if (i >= B_SIZE * EMB_DIM) return;
    int b = i / EMB_DIM;
    int d = i - b * EMB_DIM;
    int h = all_h[b];
    int r = all_r[b];
    float re_h = eemb[h * TWO_D + d];
    float im_h = eemb[h * TWO_D + EMB_DIM + d];
    float ph = remb[r * EMB_DIM + d] * PHASE_SCALE;
    float s, c;
    sincosf(ph, &s, &c);
    int base = ((b * D4 + (d >> 2)) << 3) + (d & 3);
    rot[base]     = __float2half(re_h * c - im_h * s);  // re_rot
    rot[base + 4] = __float2half(re_h * s + im_h * c);  // im_rot
}

// ---------------------------------------------------------------------------
// Kernel 2: one block = 16 entities (4 per wave) -> 64 accumulators/lane.
// v[64] + 16 staging regs wants ~160-200 VGPRs: NO second launch_bounds arg.
// Evidence: (256,4) cap -> allocator targets 64 VGPR and spills (R3: 109 MB
// scratch writes, 106us; R5 v[32] no-spill but only 8 evals per LDS read ->
// latency-exposed, 97us). R2 (4 ents, AGPR-lucky spill) = 39.8us best.
// ---------------------------------------------------------------------------
__global__ __launch_bounds__(256) void rotate_score(
    const float* __restrict__ eemb,
    const __half* __restrict__ rot,      // nullptr -> compute in-kernel
    const int* __restrict__ all_h, const int* __restrict__ all_r,
    const float* __restrict__ remb,
    float* __restrict__ out)
{
    __shared__ __half lrot[ROT_HALFS];   // 32000 bytes

    const int tid = threadIdx.x;

    if (rot != nullptr) {
        const float4* src = (const float4*)rot;
        float4* dst = (float4*)lrot;
        for (int i = tid; i < ROT_HALFS / 8; i += 256) dst[i] = src[i];
    } else {
        for (int i = tid; i < B_SIZE * EMB_DIM; i += 256) {
            int b = i / EMB_DIM;
            int d = i - b * EMB_DIM;
            int h = all_h[b];
            int r = all_r[b];
            float re_h = eemb[h * TWO_D + d];
            float im_h = eemb[h * TWO_D + EMB_DIM + d];
            float ph = remb[r * EMB_DIM + d] * PHASE_SCALE;
            float s, c;
            sincosf(ph, &s, &c);
            int base = ((b * D4 + (d >> 2)) << 3) + (d & 3);
            lrot[base]     = __float2half(re_h * c - im_h * s);
            lrot[base + 4] = __float2half(re_h * s + im_h * c);
        }
    }
    __syncthreads();

    const int lane = tid & 63;
    const int wave = tid >> 6;
    const int e0 = blockIdx.x * ENT_PER_BLOCK + wave * ENT_PER_WAVE;

    int e[ENT_PER_WAVE];
#pragma unroll
    for (int k = 0; k < ENT_PER_WAVE; ++k) {
        int ek = e0 + k;
        e[k] = (ek < NUM_ENTITIES) ? ek : (NUM_ENTITIES - 1);
    }

    float v[64];                         // acc[k][b]: idx = k*16+b
#pragma unroll
    for (int i = 0; i < 64; ++i) v[i] = 0.0f;

    const float4* lrot4 = (const float4*)lrot;
    const float4* ee4 = (const float4*)eemb;

#pragma unroll
    for (int it = 0; it < 2; ++it) {
        const int d4 = it * 64 + lane;
        if (d4 < D4) {
            float4 tre[ENT_PER_WAVE], tim[ENT_PER_WAVE];
#pragma unroll
            for (int k = 0; k < ENT_PER_WAVE; ++k) {
                int rb = e[k] * ROW_F4;
                tre[k] = ee4[rb + d4];
                tim[k] = ee4[rb + D4 + d4];
            }
#pragma unroll
            for (int b = 0; b < 16; ++b) {
                float4 rv = lrot4[b * D4 + d4];
                __half2 p0 = __builtin_bit_cast(__half2, rv.x);
                __half2 p1 = __builtin_bit_cast(__half2, rv.y);
                __half2 p2 = __builtin_bit_cast(__half2, rv.z);
                __half2 p3 = __builtin_bit_cast(__half2, rv.w);
                float rre0 = __low2float(p0), rre1 = __high2float(p0);
                float rre2 = __low2float(p1), rre3 = __high2float(p1);
                float rim0 = __low2float(p2), rim1 = __high2float(p2);
                float rim2 = __low2float(p3), rim3 = __high2float(p3);
#pragma unroll
                for (int k = 0; k < ENT_PER_WAVE; ++k) {
                    float dre, dim;
                    dre = rre0 - tre[k].x; dim = rim0 - tim[k].x;
                    v[k * 16 + b] += __builtin_amdgcn_sqrtf(dre * dre + dim * dim);
                    dre = rre1 - tre[k].y; dim = rim1 - tim[k].y;
                    v[k * 16 + b] += __builtin_amdgcn_sqrtf(dre * dre + dim * dim);
                    dre = rre2 - tre[k].z; dim = rim2 - tim[k].z;
                    v[k * 16 + b] += __builtin_amdgcn_sqrtf(dre * dre + dim * dim);
                    dre = rre3 - tre[k].w; dim = rim3 - tim[k].w;
                    v[k * 16 + b] += __builtin_amdgcn_sqrtf(dre * dre + dim * dim);
                }
            }
        }
    }

    // Halving butterfly: each stage exchanges complementary halves with
    // lane^m; after 6 stages lane L holds the full 64-lane sum of v[L].
#pragma unroll
    for (int m = 32; m >= 1; m >>= 1) {
        const bool hi = (lane & m) != 0;
#pragma unroll
        for (int i = 0; i < m; ++i) {
            float give = hi ? v[i] : v[m + i];
            float keep = hi ? v[m + i] : v[i];
            v[i] = keep + __shfl_xor(give, m, 64);
        }
    }

    const int kk = lane >> 4;            // 0..3
    const int bb = lane & 15;            // 0..15
    const int ee = e0 + kk;
    if (ee < NUM_ENTITIES) out[bb * NUM_ENTITIES + ee] = GAMMA_F - v[0];
}

extern "C" void kernel_launch(void* const* d_in, const int* in_sizes, int n_in,
                              void* d_out, int out_size, void* d_ws, size_t ws_size,
                              hipStream_t stream) {
    const int*   all_h = (const int*)d_in[0];
    const int*   all_r = (const int*)d_in[1];
    const float* eemb  = (const float*)d_in[2];
    const float* remb  = (const float*)d_in[3];
    float* out = (float*)d_out;

    __half* rot = nullptr;
    const size_t rot_bytes = (size_t)ROT_HALFS * sizeof(__half);
    if (ws_size >= rot_bytes) {
        rot = (__half*)d_ws;
        rot_precompute<<<(B_SIZE * EMB_DIM + 255) / 256, 256, 0, stream>>>(
            all_h, all_r, eemb, remb, rot);
    }

    int nblocks = (NUM_ENTITIES + ENT_PER_BLOCK - 1) / ENT_PER_BLOCK;  // 909
    rotate_score<<<nblocks, 256, 0, stream>>>(eemb, rot, all_h, all_r, remb, out);
}